// Round 6
// baseline (142.629 us; speedup 1.0000x reference)
//
#include <hip/hip_runtime.h>
#include <hip/hip_fp16.h>
#include <hip/hip_cooperative_groups.h>

#define BN 4096
#define DIM 256
#define NB 128               // blocks: one 32-anchor stripe each, 128 <= 256 CUs
#define MARGIN_F 0.3f
#define NEG_FILL_F 1e9f
#define HP_SENT_BITS 0xBF800000  // bits of -1.0f: "no positive seen"

typedef __attribute__((ext_vector_type(8))) _Float16 f16x8;
typedef __attribute__((ext_vector_type(4))) float f32x4;

namespace cg = cooperative_groups;

// ================= single fused cooperative kernel =================
// Theory: three dependent dispatches carry ~10us fixed cost each (launch/drain
// boundaries) -- structure-invariant ~40us remainder across R0..R5. Fuse
// everything into ONE cooperative launch (guide: hipLaunchCooperativeKernel is
// harness-supported).
//   phase 1: block b converts rows [32b,32b+32) fp32->fp16 into global Eh
//            (chunk-major [kc][row][8], 512B store runs), exact fp32 norms.
//   grid.sync()
//   phase 2: STRIPE Gram: A (32 rows x 256 K) entirely in registers (16 f16x8);
//            stream all 4096 B-rows (wave owns 512, 8 tiles of 64). Per-anchor
//            hardest-pos/neg complete within the block -> d^2-space stats, no
//            partial arrays, no reduce kernel, no cross-block atomic fan-in.
//   phase 3: block-local sqrt+hinge over its 32 rows -> 2 scalar atomicAdds ->
//            ticket -> last block finalizes out[0].
__global__ __launch_bounds__(512, 2) void tl_fused(const float* __restrict__ E,
                                                   const int* __restrict__ labels,
                                                   float* __restrict__ norms,
                                                   float* __restrict__ red,
                                                   ushort* __restrict__ Eh,
                                                   float* __restrict__ out) {
    __shared__ ushort sh[32][264];       // fp16 staging, +8 pad (16.5 KB)
    __shared__ int comb[64];             // [0:32) rowHP(int enc) [32:64) rowHN(uint enc)

    const int tid  = threadIdx.x;
    const int lane = tid & 63;
    const int wave = tid >> 6;           // 0..7
    const int quad = lane >> 4, l15 = lane & 15;
    const int b = blockIdx.x;
    const int arow0 = b * 32;

    // ---------- phase 1: fp16 panel + exact norms ----------
    #pragma unroll
    for (int r = 0; r < 4; ++r) {
        const int row = wave * 4 + r;                       // local 0..31
        float4 v = reinterpret_cast<const float4*>(E + (size_t)(arow0 + row) * DIM)[lane];
        float s = v.x * v.x + v.y * v.y + v.z * v.z + v.w * v.w;   // from fp32 (exact)
        ushort4 h = make_ushort4(__half_as_ushort(__float2half(v.x)),
                                 __half_as_ushort(__float2half(v.y)),
                                 __half_as_ushort(__float2half(v.z)),
                                 __half_as_ushort(__float2half(v.w)));
        *reinterpret_cast<ushort4*>(&sh[row][lane * 4]) = h;
        #pragma unroll
        for (int m = 32; m; m >>= 1) s += __shfl_xor(s, m, 64);
        if (lane == 0) norms[arow0 + row] = s;
    }
    if (b == 0 && tid < 3) red[tid] = 0.0f;   // [0]=sum [1]=cnt [2]=ticket
    __syncthreads();
    // write-out: 1024 (kc,row) chunks, 2/thread; fixed kc per 16-thread group
    // -> 32 consecutive rows = 512B contiguous runs per kc
    {
        const int kc = tid >> 4;                            // 0..31
        const int r0 = (tid & 15) * 2;
        #pragma unroll
        for (int q = 0; q < 2; ++q) {
            const int r = r0 + q;
            *reinterpret_cast<f16x8*>(Eh + (((size_t)(kc * BN + arow0 + r)) << 3)) =
                *reinterpret_cast<const f16x8*>(&sh[r][kc * 8]);
        }
    }

    cg::this_grid().sync();   // all Eh + norms visible device-wide

    // ---------- phase 2: stripe Gram + complete per-anchor stats ----------
    // A fragments in registers: [row-tile r=0,1][k-step s=0..7], kc = s*4+quad
    f16x8 afr[2][8];
    #pragma unroll
    for (int r = 0; r < 2; ++r)
        #pragma unroll
        for (int s = 0; s < 8; ++s) {
            const int kc = s * 4 + quad;
            afr[r][s] = *reinterpret_cast<const f16x8*>(
                Eh + (((size_t)(kc * BN + arow0 + r * 16 + l15)) << 3));
        }
    // C-row metadata: rows r*16 + quad*4 + e  [C layout m89/m91: col=l15, row=quad*4+reg]
    float nrow[2][4]; int lrow[2][4];
    #pragma unroll
    for (int r = 0; r < 2; ++r)
        #pragma unroll
        for (int e = 0; e < 4; ++e) {
            const int g = arow0 + r * 16 + quad * 4 + e;
            nrow[r][e] = norms[g];
            lrow[r][e] = labels[g];
        }
    float rmax[2][4], rmin[2][4];
    #pragma unroll
    for (int r = 0; r < 2; ++r)
        #pragma unroll
        for (int e = 0; e < 4; ++e) { rmax[r][e] = -1.0f; rmin[r][e] = NEG_FILL_F; }

    for (int jt = 0; jt < 8; ++jt) {                // wave's 512 B-rows, tiles of 64
        const int jbase = wave * 512 + jt * 64;
        float ncol[4]; int lcol[4];
        #pragma unroll
        for (int c = 0; c < 4; ++c) {
            const int g = jbase + c * 16 + l15;
            ncol[c] = norms[g];
            lcol[c] = labels[g];
        }
        f32x4 acc[2][4];
        #pragma unroll
        for (int r = 0; r < 2; ++r)
            #pragma unroll
            for (int c = 0; c < 4; ++c)
                acc[r][c] = (f32x4){0.f, 0.f, 0.f, 0.f};
        #pragma unroll
        for (int s = 0; s < 8; ++s) {
            const int kc = s * 4 + quad;
            f16x8 bf[4];
            #pragma unroll
            for (int c = 0; c < 4; ++c)
                bf[c] = *reinterpret_cast<const f16x8*>(
                    Eh + (((size_t)(kc * BN + jbase + c * 16 + l15)) << 3));
            #pragma unroll
            for (int c = 0; c < 4; ++c)
                #pragma unroll
                for (int r = 0; r < 2; ++r)
                    acc[r][c] = __builtin_amdgcn_mfma_f32_16x16x32_f16(afr[r][s], bf[c], acc[r][c], 0, 0, 0);
        }
        // d^2 + running masked stats (d^2 space; sqrt deferred -- monotone)
        #pragma unroll
        for (int c = 0; c < 4; ++c) {
            const int gcol = jbase + c * 16 + l15;
            #pragma unroll
            for (int r = 0; r < 2; ++r)
                #pragma unroll
                for (int e = 0; e < 4; ++e) {
                    const int grow = arow0 + r * 16 + quad * 4 + e;
                    float d2 = nrow[r][e] + ncol[c] - 2.0f * acc[r][c][e];
                    d2 = fmaxf(d2, 0.0f);
                    if (lrow[r][e] == lcol[c]) {
                        if (grow != gcol) rmax[r][e] = fmaxf(rmax[r][e], d2);
                    } else {
                        rmin[r][e] = fminf(rmin[r][e], d2);
                    }
                }
        }
    }

    // collapse cols: lanes sharing (quad) hold same rows, different cols (l15)
    #pragma unroll
    for (int m = 1; m <= 8; m <<= 1)
        #pragma unroll
        for (int r = 0; r < 2; ++r)
            #pragma unroll
            for (int e = 0; e < 4; ++e) {
                rmax[r][e] = fmaxf(rmax[r][e], __shfl_xor(rmax[r][e], m, 64));
                rmin[r][e] = fminf(rmin[r][e], __shfl_xor(rmin[r][e], m, 64));
            }
    // combine across 8 waves in LDS (CU-local atomics; int enc orders -1 sentinel)
    if (tid < 32) {
        comb[tid]      = (int)HP_SENT_BITS;
        comb[32 + tid] = (int)__float_as_uint(NEG_FILL_F);
    }
    __syncthreads();
    if (l15 == 0) {   // lanes 0,16,32,48: rows r*16 + quad*4 + e
        #pragma unroll
        for (int r = 0; r < 2; ++r)
            #pragma unroll
            for (int e = 0; e < 4; ++e) {
                const int lr = r * 16 + quad * 4 + e;
                atomicMax(&comb[lr], __float_as_int(rmax[r][e]));
                atomicMin(reinterpret_cast<unsigned*>(&comb[32 + lr]), __float_as_uint(rmin[r][e]));
            }
    }
    __syncthreads();

    // ---------- phase 3: block-local loss, scalar fan-in, ticket finalize ----------
    if (tid < 32) {
        const float hp2 = __int_as_float(comb[tid]);
        const float hn2 = __uint_as_float(((unsigned*)comb)[32 + tid]);
        const bool valid = (hp2 >= 0.0f) && (hn2 < NEG_FILL_F);    // has_pos && has_neg
        const float per = fmaxf(sqrtf(fmaxf(hp2, 0.0f)) - sqrtf(hn2) + MARGIN_F, 0.0f);
        float s_ = valid ? per : 0.0f;
        float c_ = valid ? 1.0f : 0.0f;
        #pragma unroll
        for (int m = 1; m <= 16; m <<= 1) {      // reduce over lanes 0..31
            s_ += __shfl_xor(s_, m, 64);
            c_ += __shfl_xor(c_, m, 64);
        }
        if (tid == 0) {
            atomicAdd(&red[0], s_);
            atomicAdd(&red[1], c_);
            __threadfence();
            const unsigned ticket = atomicAdd(reinterpret_cast<unsigned*>(&red[2]), 1u);
            if (ticket == NB - 1) {              // last block finalizes
                const float S = atomicAdd(&red[0], 0.0f);   // atomic read (RMW-ordered)
                const float C = atomicAdd(&red[1], 0.0f);
                out[0] = (C > 0.0f) ? (S / fmaxf(C, 1.0f)) : 0.0f;
            }
        }
    }
}

extern "C" void kernel_launch(void* const* d_in, const int* in_sizes, int n_in,
                              void* d_out, int out_size, void* d_ws, size_t ws_size,
                              hipStream_t stream) {
    const float* E      = (const float*)d_in[0];
    const int*   labels = (const int*)d_in[1];

    float*  ws    = (float*)d_ws;
    float*  norms = ws;                            // [4096] f32
    float*  red   = ws + 4096;                     // [3] f32 (sum, cnt, ticket)
    ushort* Eh    = (ushort*)(ws + 8192);          // [32][4096][8] f16 = 2 MB
    float*  o     = (float*)d_out;

    void* kargs[] = {(void*)&E, (void*)&labels, (void*)&norms,
                     (void*)&red, (void*)&Eh, (void*)&o};
    hipLaunchCooperativeKernel(reinterpret_cast<void*>(tl_fused),
                               dim3(NB), dim3(512), kargs, 0, stream);
}

// Round 7
// 84.701 us; speedup vs baseline: 1.6839x; 1.6839x over previous
//
#include <hip/hip_runtime.h>
#include <hip/hip_fp16.h>

#define BN 4096
#define DIM 256
#define NBLK 32              // 4096/128 row-blocks
#define NPAIR 528            // NBLK*(NBLK+1)/2 upper-tri block pairs
#define MARGIN_F 0.3f
#define NEG_FILL_F 1e9f
#define HP_SENT_BITS 0xBF800000  // bits of -1.0f: "no positive seen"

typedef __attribute__((ext_vector_type(8))) _Float16 f16x8;
typedef __attribute__((ext_vector_type(4))) float f32x4;

// ---------------- prep: norms (exact fp32) + red zero + fp16 panel ---------------
// Eh global layout is chunk-major: [kc = k/8][row][8 f16], 16B per (kc,row) chunk.
// Stores staged through LDS: 16B/lane, 4-row (64B) contiguity per kc.
__global__ __launch_bounds__(256) void tl_prep(const float* __restrict__ E,
                                               float* __restrict__ norms,
                                               float* __restrict__ red,
                                               ushort* __restrict__ Eh) {
    __shared__ ushort sh[4][272];            // 272-pad: 544B row stride, 16B-aligned
    const int tid  = threadIdx.x;
    const int lane = tid & 63;
    const int wrow = tid >> 6;               // 0..3: row within block
    const int row0 = blockIdx.x * 4;
    const int row  = row0 + wrow;

    float4 v = reinterpret_cast<const float4*>(E + (size_t)row * DIM)[lane];
    float f[4] = {v.x, v.y, v.z, v.w};
    ushort hb[4];
    float s = 0.0f;
    #pragma unroll
    for (int q = 0; q < 4; ++q) {
        s += f[q] * f[q];                       // norm from ORIGINAL fp32 (exact)
        hb[q] = __half_as_ushort(__float2half(f[q]));   // RN convert
    }
    *reinterpret_cast<ushort4*>(&sh[wrow][lane * 4]) = make_ushort4(hb[0], hb[1], hb[2], hb[3]);

    #pragma unroll
    for (int m = 32; m; m >>= 1) s += __shfl_xor(s, m, 64);
    if (lane == 0) norms[row] = s;
    if (blockIdx.x == 0 && tid < 3) red[tid] = 0.0f;  // [0]=sum [1]=cnt [2]=ticket

    __syncthreads();
    // 4 rows x 32 kc = 128 chunks of 16B; threads 0..127, rows fastest -> 64B runs
    if (tid < 128) {
        const int kc = tid >> 2, r = tid & 3;
        const f16x8 frag = *reinterpret_cast<const f16x8*>(&sh[r][kc * 8]);
        *reinterpret_cast<f16x8*>(Eh + (((size_t)(kc * BN + row0 + r)) << 3)) = frag;
    }
}

// ---------------- main: fp16 MFMA Gram, operands direct from L2, 8 waves/block ---
// TLP-vs-MSHR discriminating round: same 528 pair-blocks and identical total
// MFMA/operand traffic as R4, but 512 threads / 8 waves per block, each wave a
// 64x32 sub-tile. Wave supply 2112 -> 4224 (= ~4 waves/SIMD; launch_bounds(512,4)
// keeps regs <=128 so 2 blocks/CU stay resident). If main was TLP-starved this
// ~halves its time; if per-CU miss-handling (MSHR) limited, it stays flat and the
// next step is LDS staging so each line is fetched once per block.
__global__ __launch_bounds__(512, 4) void tl_main(const ushort* __restrict__ Eh,
                                                  const int* __restrict__ labels,
                                                  const float* __restrict__ norms,
                                                  float* __restrict__ pHP,
                                                  float* __restrict__ pHN) {
    __shared__ int comb[512];            // [0:128) rHP [128) rHN [256) cHP [384) cHN

    const int tid  = threadIdx.x;
    const int lane = tid & 63;
    const int wave = tid >> 6;           // 0..7
    const int wy = wave >> 2;            // 0..1: 64-row half
    const int wx = wave & 3;             // 0..3: 32-col quarter
    const int quad = lane >> 4, l15 = lane & 15;

    // decode blockIdx -> (ib <= jb) upper-tri pair
    int t = blockIdx.x, ib = 0, off = 0;
    while (off + (NBLK - ib) <= t) { off += NBLK - ib; ++ib; }
    const int jb = ib + (t - off);
    const int i0 = ib * 128, j0 = jb * 128;

    f32x4 acc[4][2];
    #pragma unroll
    for (int r = 0; r < 4; ++r)
        #pragma unroll
        for (int c = 0; c < 2; ++c)
            acc[r][c] = (f32x4){0.f, 0.f, 0.f, 0.f};

    // per-lane fragment addresses: chunk kc = s*4 + quad (ushort units)
    const ushort* baseQ = Eh + (size_t)quad * (BN * 8);
    int rA[4], rB[2];
    #pragma unroll
    for (int r = 0; r < 4; ++r) rA[r] = (i0 + wy * 64 + r * 16 + l15) * 8;
    #pragma unroll
    for (int c = 0; c < 2; ++c) rB[c] = (j0 + wx * 32 + c * 16 + l15) * 8;

    // single-buffered K loop: 8 steps of K=32; TLP (4 waves/SIMD) hides latency
    #pragma unroll
    for (int s = 0; s < 8; ++s) {
        const size_t so = (size_t)s * (4u * BN * 8u);
        f16x8 a[4], b[2];
        #pragma unroll
        for (int r = 0; r < 4; ++r)
            a[r] = *reinterpret_cast<const f16x8*>(baseQ + so + (size_t)rA[r]);
        #pragma unroll
        for (int c = 0; c < 2; ++c)
            b[c] = *reinterpret_cast<const f16x8*>(baseQ + so + (size_t)rB[c]);
        #pragma unroll
        for (int c = 0; c < 2; ++c)
            #pragma unroll
            for (int r = 0; r < 4; ++r)
                acc[r][c] = __builtin_amdgcn_mfma_f32_16x16x32_f16(a[r], b[c], acc[r][c], 0, 0, 0);
    }

    // ---- epilogue: dots -> d^2 -> masked row & col stats (d^2 space; sqrt later)
    // C layout (16x16x32): col = lane&15, row = quad*4 + reg  [m89/m91, dtype-indep]
    const int rowBase = i0 + wy * 64;
    const int colBase = j0 + wx * 32;

    int*      srhp = comb;                                   // [128]
    unsigned* srhn = reinterpret_cast<unsigned*>(comb + 128);
    int*      schp = comb + 256;
    unsigned* schn = reinterpret_cast<unsigned*>(comb + 384);
    if (tid < 128) {
        srhp[tid] = (int)HP_SENT_BITS;
        srhn[tid] = __float_as_uint(NEG_FILL_F);
        schp[tid] = (int)HP_SENT_BITS;
        schn[tid] = __float_as_uint(NEG_FILL_F);
    }
    __syncthreads();          // comb ready before any lane's atomics

    float ncol[2]; int lcol[2];
    #pragma unroll
    for (int c = 0; c < 2; ++c) {
        const int g = colBase + c * 16 + l15;
        ncol[c] = norms[g];
        lcol[c] = labels[g];
    }
    float cmax[2], cmin[2];
    #pragma unroll
    for (int c = 0; c < 2; ++c) { cmax[c] = -1.0f; cmin[c] = NEG_FILL_F; }

    #pragma unroll
    for (int r = 0; r < 4; ++r) {
        float nrow[4]; int lrow[4];
        #pragma unroll
        for (int e = 0; e < 4; ++e) {
            const int g = rowBase + r * 16 + quad * 4 + e;
            nrow[e] = norms[g];
            lrow[e] = labels[g];
        }
        float rmax[4], rmin[4];
        #pragma unroll
        for (int e = 0; e < 4; ++e) { rmax[e] = -1.0f; rmin[e] = NEG_FILL_F; }

        #pragma unroll
        for (int c = 0; c < 2; ++c) {
            const int gcol = colBase + c * 16 + l15;
            #pragma unroll
            for (int e = 0; e < 4; ++e) {
                const int grow = rowBase + r * 16 + quad * 4 + e;
                float d2 = nrow[e] + ncol[c] - 2.0f * acc[r][c][e];
                d2 = fmaxf(d2, 0.0f);            // d==0 <=> d2==0: guard-free
                if (lrow[e] == lcol[c]) {
                    if (grow != gcol) {
                        rmax[e] = fmaxf(rmax[e], d2);
                        cmax[c] = fmaxf(cmax[c], d2);
                    }
                } else {
                    rmin[e] = fminf(rmin[e], d2);
                    cmin[c] = fminf(cmin[c], d2);
                }
            }
        }
        #pragma unroll
        for (int m = 1; m <= 8; m <<= 1) {      // collapse cols (lane bits 0..3)
            #pragma unroll
            for (int e = 0; e < 4; ++e) {
                rmax[e] = fmaxf(rmax[e], __shfl_xor(rmax[e], m, 64));
                rmin[e] = fminf(rmin[e], __shfl_xor(rmin[e], m, 64));
            }
        }
        if (l15 == 0) {   // lanes 0,16,32,48 hold this r's row results per quad
            #pragma unroll
            for (int e = 0; e < 4; ++e) {
                const int lr = wy * 64 + r * 16 + quad * 4 + e;
                atomicMax(&srhp[lr], __float_as_int(rmax[e]));
                atomicMin(&srhn[lr], __float_as_uint(rmin[e]));
            }
        }
    }

    #pragma unroll
    for (int m = 16; m <= 32; m <<= 1) {        // collapse rows (quad bits)
        #pragma unroll
        for (int c = 0; c < 2; ++c) {
            cmax[c] = fmaxf(cmax[c], __shfl_xor(cmax[c], m, 64));
            cmin[c] = fminf(cmin[c], __shfl_xor(cmin[c], m, 64));
        }
    }
    if (quad == 0) {  // lanes 0..15 hold col results
        #pragma unroll
        for (int c = 0; c < 2; ++c) {
            const int lc = wx * 32 + c * 16 + l15;
            atomicMax(&schp[lc], __float_as_int(cmax[c]));
            atomicMin(&schn[lc], __float_as_uint(cmin[c]));
        }
    }
    __syncthreads();
    if (tid < 128) {
        float rp = __int_as_float(srhp[tid]);
        float rn = __uint_as_float(srhn[tid]);
        const float cp = __int_as_float(schp[tid]);
        const float cn = __uint_as_float(schn[tid]);
        if (ib == jb) {
            pHP[(size_t)jb * BN + i0 + tid] = fmaxf(rp, cp);   // diagonal: combine
            pHN[(size_t)jb * BN + i0 + tid] = fminf(rn, cn);
        } else {
            pHP[(size_t)jb * BN + i0 + tid] = rp;   // row-part -> slot jb
            pHN[(size_t)jb * BN + i0 + tid] = rn;
            pHP[(size_t)ib * BN + j0 + tid] = cp;   // col-part -> slot ib
            pHN[(size_t)ib * BN + j0 + tid] = cn;
        }
    }
}

// ------- reduce: fold 32 d^2 partial slots per row (4-way parallel per row),
//         sqrt once, accumulate loss, last block finalizes ----------------------
__global__ __launch_bounds__(256) void tl_reduce(const float* __restrict__ pHP,
                                                 const float* __restrict__ pHN,
                                                 float* __restrict__ red,
                                                 float* __restrict__ out) {
    __shared__ float shp[4][64], shn[4][64];
    const int rl = threadIdx.x & 63;                 // row within block
    const int g  = threadIdx.x >> 6;                 // slot-group 0..3 (8 slots each)
    const int i  = blockIdx.x * 64 + rl;
    float hp2 = -1.0f, hn2 = NEG_FILL_F;
    #pragma unroll
    for (int q = 0; q < 8; ++q) {
        const int s = g * 8 + q;
        hp2 = fmaxf(hp2, pHP[(size_t)s * BN + i]);   // coalesced per 64-lane group
        hn2 = fminf(hn2, pHN[(size_t)s * BN + i]);
    }
    shp[g][rl] = hp2;
    shn[g][rl] = hn2;
    __syncthreads();
    if (g == 0) {                                    // wave 0 finishes 64 rows
        #pragma unroll
        for (int k = 1; k < 4; ++k) {
            hp2 = fmaxf(hp2, shp[k][rl]);
            hn2 = fminf(hn2, shn[k][rl]);
        }
        const bool valid = (hp2 >= 0.0f) && (hn2 < NEG_FILL_F);  // has_pos && has_neg
        const float hp = sqrtf(fmaxf(hp2, 0.0f));    // sqrt(max d^2) == max d (monotone)
        const float hn = sqrtf(hn2);
        const float per = fmaxf(hp - hn + MARGIN_F, 0.0f);
        float s_ = valid ? per : 0.0f;
        float c_ = valid ? 1.0f : 0.0f;
        #pragma unroll
        for (int m = 32; m; m >>= 1) {
            s_ += __shfl_xor(s_, m, 64);
            c_ += __shfl_xor(c_, m, 64);
        }
        if (rl == 0) {
            atomicAdd(&red[0], s_);
            atomicAdd(&red[1], c_);
            __threadfence();
            const unsigned ticket = atomicAdd(reinterpret_cast<unsigned*>(&red[2]), 1u);
            if (ticket == gridDim.x - 1) {           // last block finalizes
                const float S2 = atomicAdd(&red[0], 0.0f);   // atomic read (RMW-ordered)
                const float C2 = atomicAdd(&red[1], 0.0f);
                out[0] = (C2 > 0.0f) ? (S2 / fmaxf(C2, 1.0f)) : 0.0f;
            }
        }
    }
}

extern "C" void kernel_launch(void* const* d_in, const int* in_sizes, int n_in,
                              void* d_out, int out_size, void* d_ws, size_t ws_size,
                              hipStream_t stream) {
    const float* E      = (const float*)d_in[0];
    const int*   labels = (const int*)d_in[1];

    float*  ws    = (float*)d_ws;
    float*  norms = ws;                            // [4096] f32
    float*  red   = ws + 4096;                     // [3] f32 (sum, cnt, ticket)
    float*  pHP   = ws + 8192;                     // [32][4096] f32 = 512 KB (d^2)
    float*  pHN   = ws + 8192 + NBLK * BN;         // [32][4096] f32 = 512 KB (d^2)
    ushort* Eh    = (ushort*)(ws + 8192 + 2 * NBLK * BN);  // [32][4096][8] f16 = 2 MB

    tl_prep<<<BN / 4, 256, 0, stream>>>(E, norms, red, Eh);
    tl_main<<<NPAIR, 512, 0, stream>>>(Eh, labels, norms, pHP, pHN);
    tl_reduce<<<BN / 64, 256, 0, stream>>>(pHP, pHN, red, (float*)d_out);
}

// Round 9
// 83.237 us; speedup vs baseline: 1.7135x; 1.0176x over previous
//
#include <hip/hip_runtime.h>
#include <hip/hip_fp16.h>

#define BN 4096
#define DIM 256
#define NBLK 32              // 4096/128 row-blocks
#define NPAIR 528            // NBLK*(NBLK+1)/2 upper-tri block pairs
#define MARGIN_F 0.3f
#define NEG_FILL_F 1e9f
#define HP_SENT_BITS 0xBF800000  // bits of -1.0f: "no positive seen"

typedef __attribute__((ext_vector_type(8))) _Float16 f16x8;
typedef __attribute__((ext_vector_type(4))) float f32x4;

// ---------------- prep: norms (exact fp32) + red zero + fp16 panel ---------------
// Eh global layout is chunk-major: [kc = k/8][row][8 f16], 16B per (kc,row) chunk.
// Stores staged through LDS: 16B/lane, 4-row (64B) contiguity per kc.
__global__ __launch_bounds__(256) void tl_prep(const float* __restrict__ E,
                                               float* __restrict__ norms,
                                               float* __restrict__ red,
                                               ushort* __restrict__ Eh) {
    __shared__ ushort sh[4][272];            // 272-pad: 544B row stride, 16B-aligned
    const int tid  = threadIdx.x;
    const int lane = tid & 63;
    const int wrow = tid >> 6;               // 0..3: row within block
    const int row0 = blockIdx.x * 4;
    const int row  = row0 + wrow;

    float4 v = reinterpret_cast<const float4*>(E + (size_t)row * DIM)[lane];
    float f[4] = {v.x, v.y, v.z, v.w};
    ushort hb[4];
    float s = 0.0f;
    #pragma unroll
    for (int q = 0; q < 4; ++q) {
        s += f[q] * f[q];                       // norm from ORIGINAL fp32 (exact)
        hb[q] = __half_as_ushort(__float2half(f[q]));   // RN convert
    }
    *reinterpret_cast<ushort4*>(&sh[wrow][lane * 4]) = make_ushort4(hb[0], hb[1], hb[2], hb[3]);

    #pragma unroll
    for (int m = 32; m; m >>= 1) s += __shfl_xor(s, m, 64);
    if (lane == 0) norms[row] = s;
    if (blockIdx.x == 0 && tid < 3) red[tid] = 0.0f;  // [0]=sum [1]=cnt [2]=ticket

    __syncthreads();
    // 4 rows x 32 kc = 128 chunks of 16B; threads 0..127, rows fastest -> 64B runs
    if (tid < 128) {
        const int kc = tid >> 2, r = tid & 3;
        const f16x8 frag = *reinterpret_cast<const f16x8*>(&sh[r][kc * 8]);
        *reinterpret_cast<f16x8*>(Eh + (((size_t)(kc * BN + row0 + r)) << 3)) = frag;
    }
}

// ---------------- prefetch: full-coverage, max-concurrency cache re-warm ---------
// (Resubmit of R7's proposal -- R8 bench was an infra failure, no data.)
// The harness's 256MiB poison fill evicts L2+L3 every iteration; main's first
// touches are demand misses behind dependent MFMA chains (R6/R7: time is
// independent of wave supply -> memory-path serialization). This kernel refills
// the whole 2MB Eh (+ norms/labels) as one flat burst: 131072 independent
// threads x one 16B chunk each, ~32K lines in flight grid-wide, no consumers.
// L3 (memory-side) dedups the per-XCD HBM refetch (R3: FETCH 8.45MB ~ 4x Eh).
// asm sinks keep the loads live (DCE rule: a value with no use is deleted).
// NOTE: R5's warm-touch probe covered only 1/4 of Eh (stride bug) -- this is
// the correct full-coverage test of the cold-refill theory.
__global__ __launch_bounds__(256) void tl_prefetch(const ushort* __restrict__ Eh,
                                                   const float* __restrict__ norms,
                                                   const int* __restrict__ labels) {
    const size_t idx = (size_t)blockIdx.x * 256 + threadIdx.x;   // 0..131071
    const uint4 v = reinterpret_cast<const uint4*>(Eh)[idx];     // 16B each = 2MB
    asm volatile("" :: "v"(v.x), "v"(v.y), "v"(v.z), "v"(v.w));
    if (blockIdx.x < 4) {                     // norms: 4096 f32 = 1024 float4
        const int t = blockIdx.x * 256 + threadIdx.x;
        const float4 n = reinterpret_cast<const float4*>(norms)[t];
        asm volatile("" :: "v"(n.x), "v"(n.y), "v"(n.z), "v"(n.w));
    } else if (blockIdx.x < 8) {              // labels: 4096 i32 = 1024 int4
        const int t = (blockIdx.x - 4) * 256 + threadIdx.x;
        const int4 l = reinterpret_cast<const int4*>(labels)[t];
        asm volatile("" :: "v"(l.x), "v"(l.y), "v"(l.z), "v"(l.w));
    }
}

// ---------------- main: fp16 MFMA Gram, operands direct from L2, 4 waves/block ---
// One block per upper-tri 128x128 pair, 4 waves each owning a 64x64 sub-tile.
// Single-buffered fragments, no operand LDS, no main-loop barriers (best measured
// structure: R4 = 79.4us total). R6/R7 falsified TLP-starvation; this round
// pairs it with tl_prefetch to attack the cold-miss latency component.
__global__ __launch_bounds__(256, 4) void tl_main(const ushort* __restrict__ Eh,
                                                  const int* __restrict__ labels,
                                                  const float* __restrict__ norms,
                                                  float* __restrict__ pHP,
                                                  float* __restrict__ pHN) {
    __shared__ int comb[512];            // [0:128) rHP [128) rHN [256) cHP [384) cHN

    const int tid  = threadIdx.x;
    const int lane = tid & 63;
    const int wave = tid >> 6;
    const int wy = wave >> 1, wx = wave & 1;
    const int quad = lane >> 4, l15 = lane & 15;

    // decode blockIdx -> (ib <= jb) upper-tri pair
    int t = blockIdx.x, ib = 0, off = 0;
    while (off + (NBLK - ib) <= t) { off += NBLK - ib; ++ib; }
    const int jb = ib + (t - off);
    const int i0 = ib * 128, j0 = jb * 128;

    f32x4 acc[4][4];
    #pragma unroll
    for (int r = 0; r < 4; ++r)
        #pragma unroll
        for (int c = 0; c < 4; ++c)
            acc[r][c] = (f32x4){0.f, 0.f, 0.f, 0.f};

    // per-lane fragment addresses: chunk kc = s*4 + quad (ushort units)
    const ushort* baseQ = Eh + (size_t)quad * (BN * 8);
    int rA[4], rB[4];
    #pragma unroll
    for (int r = 0; r < 4; ++r) rA[r] = (i0 + wy * 64 + r * 16 + l15) * 8;
    #pragma unroll
    for (int c = 0; c < 4; ++c) rB[c] = (j0 + wx * 64 + c * 16 + l15) * 8;

    // single-buffered K loop: 8 steps of K=32
    #pragma unroll
    for (int s = 0; s < 8; ++s) {
        const size_t so = (size_t)s * (4u * BN * 8u);
        f16x8 a[4], b[4];
        #pragma unroll
        for (int r = 0; r < 4; ++r)
            a[r] = *reinterpret_cast<const f16x8*>(baseQ + so + (size_t)rA[r]);
        #pragma unroll
        for (int c = 0; c < 4; ++c)
            b[c] = *reinterpret_cast<const f16x8*>(baseQ + so + (size_t)rB[c]);
        #pragma unroll
        for (int c = 0; c < 4; ++c)
            #pragma unroll
            for (int r = 0; r < 4; ++r)
                acc[r][c] = __builtin_amdgcn_mfma_f32_16x16x32_f16(a[r], b[c], acc[r][c], 0, 0, 0);
    }

    // ---- epilogue: dots -> d^2 -> masked row & col stats (d^2 space; sqrt later)
    // C layout (16x16x32): col = lane&15, row = quad*4 + reg  [m89/m91, dtype-indep]
    const int rowBase = i0 + wy * 64;
    const int colBase = j0 + wx * 64;

    int*      srhp = comb;                                   // [128]
    unsigned* srhn = reinterpret_cast<unsigned*>(comb + 128);
    int*      schp = comb + 256;
    unsigned* schn = reinterpret_cast<unsigned*>(comb + 384);
    if (tid < 128) {
        srhp[tid] = (int)HP_SENT_BITS;
        srhn[tid] = __float_as_uint(NEG_FILL_F);
        schp[tid] = (int)HP_SENT_BITS;
        schn[tid] = __float_as_uint(NEG_FILL_F);
    }
    __syncthreads();          // comb ready before any lane's atomics

    float ncol[4]; int lcol[4];
    #pragma unroll
    for (int c = 0; c < 4; ++c) {
        const int g = colBase + c * 16 + l15;
        ncol[c] = norms[g];
        lcol[c] = labels[g];
    }
    float cmax[4], cmin[4];
    #pragma unroll
    for (int c = 0; c < 4; ++c) { cmax[c] = -1.0f; cmin[c] = NEG_FILL_F; }

    #pragma unroll
    for (int r = 0; r < 4; ++r) {
        float nrow[4]; int lrow[4];
        #pragma unroll
        for (int e = 0; e < 4; ++e) {
            const int g = rowBase + r * 16 + quad * 4 + e;
            nrow[e] = norms[g];
            lrow[e] = labels[g];
        }
        float rmax[4], rmin[4];
        #pragma unroll
        for (int e = 0; e < 4; ++e) { rmax[e] = -1.0f; rmin[e] = NEG_FILL_F; }

        #pragma unroll
        for (int c = 0; c < 4; ++c) {
            const int gcol = colBase + c * 16 + l15;
            #pragma unroll
            for (int e = 0; e < 4; ++e) {
                const int grow = rowBase + r * 16 + quad * 4 + e;
                float d2 = nrow[e] + ncol[c] - 2.0f * acc[r][c][e];
                d2 = fmaxf(d2, 0.0f);            // d==0 <=> d2==0: guard-free
                if (lrow[e] == lcol[c]) {
                    if (grow != gcol) {
                        rmax[e] = fmaxf(rmax[e], d2);
                        cmax[c] = fmaxf(cmax[c], d2);
                    }
                } else {
                    rmin[e] = fminf(rmin[e], d2);
                    cmin[c] = fminf(cmin[c], d2);
                }
            }
        }
        #pragma unroll
        for (int m = 1; m <= 8; m <<= 1) {      // collapse cols (lane bits 0..3)
            #pragma unroll
            for (int e = 0; e < 4; ++e) {
                rmax[e] = fmaxf(rmax[e], __shfl_xor(rmax[e], m, 64));
                rmin[e] = fminf(rmin[e], __shfl_xor(rmin[e], m, 64));
            }
        }
        if (l15 == 0) {   // lanes 0,16,32,48 hold this r's row results per quad
            #pragma unroll
            for (int e = 0; e < 4; ++e) {
                const int lr = wy * 64 + r * 16 + quad * 4 + e;
                atomicMax(&srhp[lr], __float_as_int(rmax[e]));
                atomicMin(&srhn[lr], __float_as_uint(rmin[e]));
            }
        }
    }

    #pragma unroll
    for (int m = 16; m <= 32; m <<= 1) {        // collapse rows (quad bits)
        #pragma unroll
        for (int c = 0; c < 4; ++c) {
            cmax[c] = fmaxf(cmax[c], __shfl_xor(cmax[c], m, 64));
            cmin[c] = fminf(cmin[c], __shfl_xor(cmin[c], m, 64));
        }
    }
    if (quad == 0) {  // lanes 0..15 hold col results
        #pragma unroll
        for (int c = 0; c < 4; ++c) {
            const int lc = wx * 64 + c * 16 + l15;
            atomicMax(&schp[lc], __float_as_int(cmax[c]));
            atomicMin(&schn[lc], __float_as_uint(cmin[c]));
        }
    }
    __syncthreads();
    if (tid < 128) {
        float rp = __int_as_float(srhp[tid]);
        float rn = __uint_as_float(srhn[tid]);
        const float cp = __int_as_float(schp[tid]);
        const float cn = __uint_as_float(schn[tid]);
        if (ib == jb) {
            pHP[(size_t)jb * BN + i0 + tid] = fmaxf(rp, cp);   // diagonal: combine
            pHN[(size_t)jb * BN + i0 + tid] = fminf(rn, cn);
        } else {
            pHP[(size_t)jb * BN + i0 + tid] = rp;   // row-part -> slot jb
            pHN[(size_t)jb * BN + i0 + tid] = rn;
            pHP[(size_t)ib * BN + j0 + tid] = cp;   // col-part -> slot ib
            pHN[(size_t)ib * BN + j0 + tid] = cn;
        }
    }
}

// ------- reduce: fold 32 d^2 partial slots per row (4-way parallel per row),
//         sqrt once, accumulate loss, last block finalizes ----------------------
__global__ __launch_bounds__(256) void tl_reduce(const float* __restrict__ pHP,
                                                 const float* __restrict__ pHN,
                                                 float* __restrict__ red,
                                                 float* __restrict__ out) {
    __shared__ float shp[4][64], shn[4][64];
    const int rl = threadIdx.x & 63;                 // row within block
    const int g  = threadIdx.x >> 6;                 // slot-group 0..3 (8 slots each)
    const int i  = blockIdx.x * 64 + rl;
    float hp2 = -1.0f, hn2 = NEG_FILL_F;
    #pragma unroll
    for (int q = 0; q < 8; ++q) {
        const int s = g * 8 + q;
        hp2 = fmaxf(hp2, pHP[(size_t)s * BN + i]);   // coalesced per 64-lane group
        hn2 = fminf(hn2, pHN[(size_t)s * BN + i]);
    }
    shp[g][rl] = hp2;
    shn[g][rl] = hn2;
    __syncthreads();
    if (g == 0) {                                    // wave 0 finishes 64 rows
        #pragma unroll
        for (int k = 1; k < 4; ++k) {
            hp2 = fmaxf(hp2, shp[k][rl]);
            hn2 = fminf(hn2, shn[k][rl]);
        }
        const bool valid = (hp2 >= 0.0f) && (hn2 < NEG_FILL_F);  // has_pos && has_neg
        const float hp = sqrtf(fmaxf(hp2, 0.0f));    // sqrt(max d^2) == max d (monotone)
        const float hn = sqrtf(hn2);
        const float per = fmaxf(hp - hn + MARGIN_F, 0.0f);
        float s_ = valid ? per : 0.0f;
        float c_ = valid ? 1.0f : 0.0f;
        #pragma unroll
        for (int m = 32; m; m >>= 1) {
            s_ += __shfl_xor(s_, m, 64);
            c_ += __shfl_xor(c_, m, 64);
        }
        if (rl == 0) {
            atomicAdd(&red[0], s_);
            atomicAdd(&red[1], c_);
            __threadfence();
            const unsigned ticket = atomicAdd(reinterpret_cast<unsigned*>(&red[2]), 1u);
            if (ticket == gridDim.x - 1) {           // last block finalizes
                const float S2 = atomicAdd(&red[0], 0.0f);   // atomic read (RMW-ordered)
                const float C2 = atomicAdd(&red[1], 0.0f);
                out[0] = (C2 > 0.0f) ? (S2 / fmaxf(C2, 1.0f)) : 0.0f;
            }
        }
    }
}

extern "C" void kernel_launch(void* const* d_in, const int* in_sizes, int n_in,
                              void* d_out, int out_size, void* d_ws, size_t ws_size,
                              hipStream_t stream) {
    const float* E      = (const float*)d_in[0];
    const int*   labels = (const int*)d_in[1];

    float*  ws    = (float*)d_ws;
    float*  norms = ws;                            // [4096] f32
    float*  red   = ws + 4096;                     // [3] f32 (sum, cnt, ticket)
    float*  pHP   = ws + 8192;                     // [32][4096] f32 = 512 KB (d^2)
    float*  pHN   = ws + 8192 + NBLK * BN;         // [32][4096] f32 = 512 KB (d^2)
    ushort* Eh    = (ushort*)(ws + 8192 + 2 * NBLK * BN);  // [32][4096][8] f16 = 2 MB

    tl_prep<<<BN / 4, 256, 0, stream>>>(E, norms, red, Eh);
    tl_prefetch<<<512, 256, 0, stream>>>(Eh, norms, labels);
    tl_main<<<NPAIR, 256, 0, stream>>>(Eh, labels, norms, pHP, pHN);
    tl_reduce<<<BN / 64, 256, 0, stream>>>(pHP, pHN, red, (float*)d_out);
}

// Round 10
// 80.164 us; speedup vs baseline: 1.7792x; 1.0383x over previous
//
#include <hip/hip_runtime.h>
#include <hip/hip_fp16.h>

#define BN 4096
#define DIM 256
#define PANEL 4104           // kc-panel row stride: BN + 8 rows = 64KB + 128B.
                             // Breaks the exact-64KB power-of-2 stride that parked
                             // all four quads (kc = s*4+quad) on the same L2
                             // channel set (channel interleave period ~4KB).
#define NBLK 32              // 4096/128 row-blocks
#define NPAIR 528            // NBLK*(NBLK+1)/2 upper-tri block pairs
#define MARGIN_F 0.3f
#define NEG_FILL_F 1e9f
#define HP_SENT_BITS 0xBF800000  // bits of -1.0f: "no positive seen"

typedef __attribute__((ext_vector_type(8))) _Float16 f16x8;
typedef __attribute__((ext_vector_type(4))) float f32x4;

// ---------------- prep: norms (exact fp32) + red zero + fp16 panel ---------------
// Eh global layout is chunk-major with PADDED panel stride:
//   [kc = k/8][row (stride PANEL)][8 f16], 16B per (kc,row) chunk.
// Stores staged through LDS: 16B/lane, 4-row (64B) contiguity per kc.
__global__ __launch_bounds__(256) void tl_prep(const float* __restrict__ E,
                                               float* __restrict__ norms,
                                               float* __restrict__ red,
                                               ushort* __restrict__ Eh) {
    __shared__ ushort sh[4][272];            // 272-pad: 544B row stride, 16B-aligned
    const int tid  = threadIdx.x;
    const int lane = tid & 63;
    const int wrow = tid >> 6;               // 0..3: row within block
    const int row0 = blockIdx.x * 4;
    const int row  = row0 + wrow;

    float4 v = reinterpret_cast<const float4*>(E + (size_t)row * DIM)[lane];
    float f[4] = {v.x, v.y, v.z, v.w};
    ushort hb[4];
    float s = 0.0f;
    #pragma unroll
    for (int q = 0; q < 4; ++q) {
        s += f[q] * f[q];                       // norm from ORIGINAL fp32 (exact)
        hb[q] = __half_as_ushort(__float2half(f[q]));   // RN convert
    }
    *reinterpret_cast<ushort4*>(&sh[wrow][lane * 4]) = make_ushort4(hb[0], hb[1], hb[2], hb[3]);

    #pragma unroll
    for (int m = 32; m; m >>= 1) s += __shfl_xor(s, m, 64);
    if (lane == 0) norms[row] = s;
    if (blockIdx.x == 0 && tid < 3) red[tid] = 0.0f;  // [0]=sum [1]=cnt [2]=ticket

    __syncthreads();
    // 4 rows x 32 kc = 128 chunks of 16B; threads 0..127, rows fastest -> 64B runs
    if (tid < 128) {
        const int kc = tid >> 2, r = tid & 3;
        const f16x8 frag = *reinterpret_cast<const f16x8*>(&sh[r][kc * 8]);
        *reinterpret_cast<f16x8*>(Eh + (((size_t)(kc * PANEL + row0 + r)) << 3)) = frag;
    }
}

// ---------------- main: fp16 MFMA Gram, operands direct from L2, 4 waves/block ---
// One block per upper-tri 128x128 pair, 4 waves each owning a 64x64 sub-tile.
// Single-buffered fragments, no operand LDS, no main-loop barriers (R4 structure,
// best measured: 79.4us total). R9 falsified cold-miss latency (full prefetch =
// null), R6/R7 falsified TLP, R1 falsified ILP depth. Remaining mechanism
// consistent with ALL observations (pipes idle, wave-count-independent,
// prefetch-null): L2 CHANNEL CAMPING from the exact-64KB kc-panel stride --
// every quad, every step, every block hit the same channel subset mod 4KB.
// PANEL=4104 de-aliases it (quad -> +128B, step -> +512B mod 4KB).
__global__ __launch_bounds__(256, 4) void tl_main(const ushort* __restrict__ Eh,
                                                  const int* __restrict__ labels,
                                                  const float* __restrict__ norms,
                                                  float* __restrict__ pHP,
                                                  float* __restrict__ pHN) {
    __shared__ int comb[512];            // [0:128) rHP [128) rHN [256) cHP [384) cHN

    const int tid  = threadIdx.x;
    const int lane = tid & 63;
    const int wave = tid >> 6;
    const int wy = wave >> 1, wx = wave & 1;
    const int quad = lane >> 4, l15 = lane & 15;

    // decode blockIdx -> (ib <= jb) upper-tri pair
    int t = blockIdx.x, ib = 0, off = 0;
    while (off + (NBLK - ib) <= t) { off += NBLK - ib; ++ib; }
    const int jb = ib + (t - off);
    const int i0 = ib * 128, j0 = jb * 128;

    f32x4 acc[4][4];
    #pragma unroll
    for (int r = 0; r < 4; ++r)
        #pragma unroll
        for (int c = 0; c < 4; ++c)
            acc[r][c] = (f32x4){0.f, 0.f, 0.f, 0.f};

    // per-lane fragment addresses: chunk kc = s*4 + quad (ushort units)
    const ushort* baseQ = Eh + (size_t)quad * (PANEL * 8);
    int rA[4], rB[4];
    #pragma unroll
    for (int r = 0; r < 4; ++r) rA[r] = (i0 + wy * 64 + r * 16 + l15) * 8;
    #pragma unroll
    for (int c = 0; c < 4; ++c) rB[c] = (j0 + wx * 64 + c * 16 + l15) * 8;

    // single-buffered K loop: 8 steps of K=32
    #pragma unroll
    for (int s = 0; s < 8; ++s) {
        const size_t so = (size_t)s * (4u * PANEL * 8u);
        f16x8 a[4], b[4];
        #pragma unroll
        for (int r = 0; r < 4; ++r)
            a[r] = *reinterpret_cast<const f16x8*>(baseQ + so + (size_t)rA[r]);
        #pragma unroll
        for (int c = 0; c < 4; ++c)
            b[c] = *reinterpret_cast<const f16x8*>(baseQ + so + (size_t)rB[c]);
        #pragma unroll
        for (int c = 0; c < 4; ++c)
            #pragma unroll
            for (int r = 0; r < 4; ++r)
                acc[r][c] = __builtin_amdgcn_mfma_f32_16x16x32_f16(a[r], b[c], acc[r][c], 0, 0, 0);
    }

    // ---- epilogue: dots -> d^2 -> masked row & col stats (d^2 space; sqrt later)
    // C layout (16x16x32): col = lane&15, row = quad*4 + reg  [m89/m91, dtype-indep]
    const int rowBase = i0 + wy * 64;
    const int colBase = j0 + wx * 64;

    int*      srhp = comb;                                   // [128]
    unsigned* srhn = reinterpret_cast<unsigned*>(comb + 128);
    int*      schp = comb + 256;
    unsigned* schn = reinterpret_cast<unsigned*>(comb + 384);
    if (tid < 128) {
        srhp[tid] = (int)HP_SENT_BITS;
        srhn[tid] = __float_as_uint(NEG_FILL_F);
        schp[tid] = (int)HP_SENT_BITS;
        schn[tid] = __float_as_uint(NEG_FILL_F);
    }
    __syncthreads();          // comb ready before any lane's atomics

    float ncol[4]; int lcol[4];
    #pragma unroll
    for (int c = 0; c < 4; ++c) {
        const int g = colBase + c * 16 + l15;
        ncol[c] = norms[g];
        lcol[c] = labels[g];
    }
    float cmax[4], cmin[4];
    #pragma unroll
    for (int c = 0; c < 4; ++c) { cmax[c] = -1.0f; cmin[c] = NEG_FILL_F; }

    #pragma unroll
    for (int r = 0; r < 4; ++r) {
        float nrow[4]; int lrow[4];
        #pragma unroll
        for (int e = 0; e < 4; ++e) {
            const int g = rowBase + r * 16 + quad * 4 + e;
            nrow[e] = norms[g];
            lrow[e] = labels[g];
        }
        float rmax[4], rmin[4];
        #pragma unroll
        for (int e = 0; e < 4; ++e) { rmax[e] = -1.0f; rmin[e] = NEG_FILL_F; }

        #pragma unroll
        for (int c = 0; c < 4; ++c) {
            const int gcol = colBase + c * 16 + l15;
            #pragma unroll
            for (int e = 0; e < 4; ++e) {
                const int grow = rowBase + r * 16 + quad * 4 + e;
                float d2 = nrow[e] + ncol[c] - 2.0f * acc[r][c][e];
                d2 = fmaxf(d2, 0.0f);            // d==0 <=> d2==0: guard-free
                if (lrow[e] == lcol[c]) {
                    if (grow != gcol) {
                        rmax[e] = fmaxf(rmax[e], d2);
                        cmax[c] = fmaxf(cmax[c], d2);
                    }
                } else {
                    rmin[e] = fminf(rmin[e], d2);
                    cmin[c] = fminf(cmin[c], d2);
                }
            }
        }
        #pragma unroll
        for (int m = 1; m <= 8; m <<= 1) {      // collapse cols (lane bits 0..3)
            #pragma unroll
            for (int e = 0; e < 4; ++e) {
                rmax[e] = fmaxf(rmax[e], __shfl_xor(rmax[e], m, 64));
                rmin[e] = fminf(rmin[e], __shfl_xor(rmin[e], m, 64));
            }
        }
        if (l15 == 0) {   // lanes 0,16,32,48 hold this r's row results per quad
            #pragma unroll
            for (int e = 0; e < 4; ++e) {
                const int lr = wy * 64 + r * 16 + quad * 4 + e;
                atomicMax(&srhp[lr], __float_as_int(rmax[e]));
                atomicMin(&srhn[lr], __float_as_uint(rmin[e]));
            }
        }
    }

    #pragma unroll
    for (int m = 16; m <= 32; m <<= 1) {        // collapse rows (quad bits)
        #pragma unroll
        for (int c = 0; c < 4; ++c) {
            cmax[c] = fmaxf(cmax[c], __shfl_xor(cmax[c], m, 64));
            cmin[c] = fminf(cmin[c], __shfl_xor(cmin[c], m, 64));
        }
    }
    if (quad == 0) {  // lanes 0..15 hold col results
        #pragma unroll
        for (int c = 0; c < 4; ++c) {
            const int lc = wx * 64 + c * 16 + l15;
            atomicMax(&schp[lc], __float_as_int(cmax[c]));
            atomicMin(&schn[lc], __float_as_uint(cmin[c]));
        }
    }
    __syncthreads();
    if (tid < 128) {
        float rp = __int_as_float(srhp[tid]);
        float rn = __uint_as_float(srhn[tid]);
        const float cp = __int_as_float(schp[tid]);
        const float cn = __uint_as_float(schn[tid]);
        if (ib == jb) {
            pHP[(size_t)jb * BN + i0 + tid] = fmaxf(rp, cp);   // diagonal: combine
            pHN[(size_t)jb * BN + i0 + tid] = fminf(rn, cn);
        } else {
            pHP[(size_t)jb * BN + i0 + tid] = rp;   // row-part -> slot jb
            pHN[(size_t)jb * BN + i0 + tid] = rn;
            pHP[(size_t)ib * BN + j0 + tid] = cp;   // col-part -> slot ib
            pHN[(size_t)ib * BN + j0 + tid] = cn;
        }
    }
}

// ------- reduce: fold 32 d^2 partial slots per row (4-way parallel per row),
//         sqrt once, accumulate loss, last block finalizes ----------------------
__global__ __launch_bounds__(256) void tl_reduce(const float* __restrict__ pHP,
                                                 const float* __restrict__ pHN,
                                                 float* __restrict__ red,
                                                 float* __restrict__ out) {
    __shared__ float shp[4][64], shn[4][64];
    const int rl = threadIdx.x & 63;                 // row within block
    const int g  = threadIdx.x >> 6;                 // slot-group 0..3 (8 slots each)
    const int i  = blockIdx.x * 64 + rl;
    float hp2 = -1.0f, hn2 = NEG_FILL_F;
    #pragma unroll
    for (int q = 0; q < 8; ++q) {
        const int s = g * 8 + q;
        hp2 = fmaxf(hp2, pHP[(size_t)s * BN + i]);   // coalesced per 64-lane group
        hn2 = fminf(hn2, pHN[(size_t)s * BN + i]);
    }
    shp[g][rl] = hp2;
    shn[g][rl] = hn2;
    __syncthreads();
    if (g == 0) {                                    // wave 0 finishes 64 rows
        #pragma unroll
        for (int k = 1; k < 4; ++k) {
            hp2 = fmaxf(hp2, shp[k][rl]);
            hn2 = fminf(hn2, shn[k][rl]);
        }
        const bool valid = (hp2 >= 0.0f) && (hn2 < NEG_FILL_F);  // has_pos && has_neg
        const float hp = sqrtf(fmaxf(hp2, 0.0f));    // sqrt(max d^2) == max d (monotone)
        const float hn = sqrtf(hn2);
        const float per = fmaxf(hp - hn + MARGIN_F, 0.0f);
        float s_ = valid ? per : 0.0f;
        float c_ = valid ? 1.0f : 0.0f;
        #pragma unroll
        for (int m = 32; m; m >>= 1) {
            s_ += __shfl_xor(s_, m, 64);
            c_ += __shfl_xor(c_, m, 64);
        }
        if (rl == 0) {
            atomicAdd(&red[0], s_);
            atomicAdd(&red[1], c_);
            __threadfence();
            const unsigned ticket = atomicAdd(reinterpret_cast<unsigned*>(&red[2]), 1u);
            if (ticket == gridDim.x - 1) {           // last block finalizes
                const float S2 = atomicAdd(&red[0], 0.0f);   // atomic read (RMW-ordered)
                const float C2 = atomicAdd(&red[1], 0.0f);
                out[0] = (C2 > 0.0f) ? (S2 / fmaxf(C2, 1.0f)) : 0.0f;
            }
        }
    }
}

extern "C" void kernel_launch(void* const* d_in, const int* in_sizes, int n_in,
                              void* d_out, int out_size, void* d_ws, size_t ws_size,
                              hipStream_t stream) {
    const float* E      = (const float*)d_in[0];
    const int*   labels = (const int*)d_in[1];

    float*  ws    = (float*)d_ws;
    float*  norms = ws;                            // [4096] f32
    float*  red   = ws + 4096;                     // [3] f32 (sum, cnt, ticket)
    float*  pHP   = ws + 8192;                     // [32][4096] f32 = 512 KB (d^2)
    float*  pHN   = ws + 8192 + NBLK * BN;         // [32][4096] f32 = 512 KB (d^2)
    ushort* Eh    = (ushort*)(ws + 8192 + 2 * NBLK * BN);  // [32][4104][8] f16 ~ 2.0 MB

    tl_prep<<<BN / 4, 256, 0, stream>>>(E, norms, red, Eh);
    tl_main<<<NPAIR, 256, 0, stream>>>(Eh, labels, norms, pHP, pHN);
    tl_reduce<<<BN / 64, 256, 0, stream>>>(pHP, pHN, red, (float*)d_out);
}

// Round 11
// 79.301 us; speedup vs baseline: 1.7986x; 1.0109x over previous
//
#include <hip/hip_runtime.h>
#include <hip/hip_fp16.h>

#define BN 4096
#define DIM 256
#define PANEL 4104           // kc-panel row stride (kept from R10; harmless)
#define NBLK 32              // 4096/128 row-blocks
#define NPAIR 528            // NBLK*(NBLK+1)/2 upper-tri block pairs
#define MARGIN_F 0.3f
#define NEG_FILL_F 1e9f
#define HP_SENT_BITS 0xBF800000  // bits of -1.0f: "no positive seen"

typedef __attribute__((ext_vector_type(8))) _Float16 f16x8;
typedef __attribute__((ext_vector_type(4))) float f32x4;

// async global->LDS, 16B per lane; LDS dest: wave-uniform base + lane*16
__device__ __forceinline__ void gld_lds16(const void* g, void* l) {
    __builtin_amdgcn_global_load_lds(
        (const __attribute__((address_space(1))) unsigned int*)g,
        (__attribute__((address_space(3))) unsigned int*)l, 16, 0, 0);
}

// ---------------- prep: norms (exact fp32) + red zero + fp16 panel ---------------
// Eh global layout: [kc = k/8][row (stride PANEL)][8 f16], 16B per (kc,row) chunk.
__global__ __launch_bounds__(256) void tl_prep(const float* __restrict__ E,
                                               float* __restrict__ norms,
                                               float* __restrict__ red,
                                               ushort* __restrict__ Eh) {
    __shared__ ushort sh[4][272];            // 272-pad: 544B row stride, 16B-aligned
    const int tid  = threadIdx.x;
    const int lane = tid & 63;
    const int wrow = tid >> 6;               // 0..3: row within block
    const int row0 = blockIdx.x * 4;
    const int row  = row0 + wrow;

    float4 v = reinterpret_cast<const float4*>(E + (size_t)row * DIM)[lane];
    float f[4] = {v.x, v.y, v.z, v.w};
    ushort hb[4];
    float s = 0.0f;
    #pragma unroll
    for (int q = 0; q < 4; ++q) {
        s += f[q] * f[q];                       // norm from ORIGINAL fp32 (exact)
        hb[q] = __half_as_ushort(__float2half(f[q]));   // RN convert
    }
    *reinterpret_cast<ushort4*>(&sh[wrow][lane * 4]) = make_ushort4(hb[0], hb[1], hb[2], hb[3]);

    #pragma unroll
    for (int m = 32; m; m >>= 1) s += __shfl_xor(s, m, 64);
    if (lane == 0) norms[row] = s;
    if (blockIdx.x == 0 && tid < 3) red[tid] = 0.0f;  // [0]=sum [1]=cnt [2]=ticket

    __syncthreads();
    // 4 rows x 32 kc = 128 chunks of 16B; threads 0..127, rows fastest -> 64B runs
    if (tid < 128) {
        const int kc = tid >> 2, r = tid & 3;
        const f16x8 frag = *reinterpret_cast<const f16x8*>(&sh[r][kc * 8]);
        *reinterpret_cast<f16x8*>(Eh + (((size_t)(kc * PANEL + row0 + r)) << 3)) = frag;
    }
}

// ---------------- main: LDS-deduped fp16 MFMA Gram, 4 blocks/CU, one round ------
// Byte-rate model (R4/R6/R9/R10): chip-level ~4 TB/s effective L2 delivery for
// this gather pattern, independent of waves/caches/ILP/interleave. The lever is
// BYTES: direct-register loads request 135 MB (2x wave redundancy); LDS staging
// via global_load_lds fetches each tile line ONCE per block -> 67 MB.
// R0's LDS version was slow because 64KB dbuf -> 2 blocks/CU -> exposed barrier
// drains + 2 residency rounds. Here: BK=32 dbuf = 32KB LDS + <=128 regs
// (launch_bounds(256,4)) -> 4 blocks/CU -> one round AND 3 sibling blocks cover
// each block's vmcnt(0)+barrier drain (m114 cross-block overlap).
__global__ __launch_bounds__(256, 4) void tl_main(const ushort* __restrict__ Eh,
                                                  const int* __restrict__ labels,
                                                  const float* __restrict__ norms,
                                                  float* __restrict__ pHP,
                                                  float* __restrict__ pHN) {
    // per buffer: A chunks [kc 0..3][m 0..127] then B chunks [kc 0..3][m 0..127],
    // 16B each -> 1024 chunks = 16 KB; double-buffered = 32 KB.
    __shared__ __align__(16) ushort smem[2][8192];
    __shared__ int comb[512];            // [0:128) rHP [128) rHN [256) cHP [384) cHN

    const int tid  = threadIdx.x;
    const int lane = tid & 63;
    const int wave = tid >> 6;
    const int wy = wave >> 1, wx = wave & 1;
    const int quad = lane >> 4, l15 = lane & 15;

    // decode blockIdx -> (ib <= jb) upper-tri pair
    int t = blockIdx.x, ib = 0, off = 0;
    while (off + (NBLK - ib) <= t) { off += NBLK - ib; ++ib; }
    const int jb = ib + (t - off);
    const int i0 = ib * 128, j0 = jb * 128;

    f32x4 acc[4][4];
    #pragma unroll
    for (int r = 0; r < 4; ++r)
        #pragma unroll
        for (int c = 0; c < 4; ++c)
            acc[r][c] = (f32x4){0.f, 0.f, 0.f, 0.f};

    // stage one BK=32 slab (A 128 rows x 4 kc + B 128 rows x 4 kc) into buf.
    // 1024 chunks of 16B; 256 threads x 4 chunks. Wave-uniform LDS base per call
    // (idx = c*256 + wave*64 + lane -> base + lane*16). Each line fetched ONCE.
    auto stage = [&](int s, int buf) {
        #pragma unroll
        for (int c = 0; c < 4; ++c) {
            const int idx  = c * 256 + tid;          // 0..1023
            const int part = idx >> 9;               // 0:A 1:B
            const int kcl  = (idx >> 7) & 3;         // kc within slab
            const int m    = idx & 127;
            const int base = part ? j0 : i0;
            const ushort* src = Eh + (((size_t)((s * 4 + kcl) * PANEL + base + m)) << 3);
            gld_lds16(src, &smem[buf][idx << 3]);
        }
    };

    stage(0, 0);
    #pragma unroll
    for (int s = 0; s < 8; ++s) {                    // 8 K-steps of 32
        const int buf = s & 1;
        __syncthreads();               // drains stage(s) vmcnt; protects buf^1
        if (s + 1 < 8) stage(s + 1, buf ^ 1);

        const ushort* sb = &smem[buf][0];
        f16x8 a[4], b[4];
        #pragma unroll
        for (int r = 0; r < 4; ++r) {
            const int mi = wy * 64 + r * 16 + l15;
            a[r] = *reinterpret_cast<const f16x8*>(&sb[(quad * 128 + mi) * 8]);
        }
        #pragma unroll
        for (int c = 0; c < 4; ++c) {
            const int ni = wx * 64 + c * 16 + l15;
            b[c] = *reinterpret_cast<const f16x8*>(&sb[(512 + quad * 128 + ni) * 8]);
        }
        #pragma unroll
        for (int c = 0; c < 4; ++c)
            #pragma unroll
            for (int r = 0; r < 4; ++r)
                acc[r][c] = __builtin_amdgcn_mfma_f32_16x16x32_f16(a[r], b[c], acc[r][c], 0, 0, 0);
    }

    // ---- epilogue: dots -> d^2 -> masked row & col stats (d^2 space; sqrt later)
    // C layout (16x16x32): col = lane&15, row = quad*4 + reg  [m89/m91, dtype-indep]
    const int rowBase = i0 + wy * 64;
    const int colBase = j0 + wx * 64;

    int*      srhp = comb;                                   // [128]
    unsigned* srhn = reinterpret_cast<unsigned*>(comb + 128);
    int*      schp = comb + 256;
    unsigned* schn = reinterpret_cast<unsigned*>(comb + 384);
    if (tid < 128) {
        srhp[tid] = (int)HP_SENT_BITS;
        srhn[tid] = __float_as_uint(NEG_FILL_F);
        schp[tid] = (int)HP_SENT_BITS;
        schn[tid] = __float_as_uint(NEG_FILL_F);
    }
    __syncthreads();          // comb ready before any lane's atomics

    float ncol[4]; int lcol[4];
    #pragma unroll
    for (int c = 0; c < 4; ++c) {
        const int g = colBase + c * 16 + l15;
        ncol[c] = norms[g];
        lcol[c] = labels[g];
    }
    float cmax[4], cmin[4];
    #pragma unroll
    for (int c = 0; c < 4; ++c) { cmax[c] = -1.0f; cmin[c] = NEG_FILL_F; }

    #pragma unroll
    for (int r = 0; r < 4; ++r) {
        float nrow[4]; int lrow[4];
        #pragma unroll
        for (int e = 0; e < 4; ++e) {
            const int g = rowBase + r * 16 + quad * 4 + e;
            nrow[e] = norms[g];
            lrow[e] = labels[g];
        }
        float rmax[4], rmin[4];
        #pragma unroll
        for (int e = 0; e < 4; ++e) { rmax[e] = -1.0f; rmin[e] = NEG_FILL_F; }

        #pragma unroll
        for (int c = 0; c < 4; ++c) {
            const int gcol = colBase + c * 16 + l15;
            #pragma unroll
            for (int e = 0; e < 4; ++e) {
                const int grow = rowBase + r * 16 + quad * 4 + e;
                float d2 = nrow[e] + ncol[c] - 2.0f * acc[r][c][e];
                d2 = fmaxf(d2, 0.0f);            // d==0 <=> d2==0: guard-free
                if (lrow[e] == lcol[c]) {
                    if (grow != gcol) {
                        rmax[e] = fmaxf(rmax[e], d2);
                        cmax[c] = fmaxf(cmax[c], d2);
                    }
                } else {
                    rmin[e] = fminf(rmin[e], d2);
                    cmin[c] = fminf(cmin[c], d2);
                }
            }
        }
        #pragma unroll
        for (int m = 1; m <= 8; m <<= 1) {      // collapse cols (lane bits 0..3)
            #pragma unroll
            for (int e = 0; e < 4; ++e) {
                rmax[e] = fmaxf(rmax[e], __shfl_xor(rmax[e], m, 64));
                rmin[e] = fminf(rmin[e], __shfl_xor(rmin[e], m, 64));
            }
        }
        if (l15 == 0) {   // lanes 0,16,32,48 hold this r's row results per quad
            #pragma unroll
            for (int e = 0; e < 4; ++e) {
                const int lr = wy * 64 + r * 16 + quad * 4 + e;
                atomicMax(&srhp[lr], __float_as_int(rmax[e]));
                atomicMin(&srhn[lr], __float_as_uint(rmin[e]));
            }
        }
    }

    #pragma unroll
    for (int m = 16; m <= 32; m <<= 1) {        // collapse rows (quad bits)
        #pragma unroll
        for (int c = 0; c < 4; ++c) {
            cmax[c] = fmaxf(cmax[c], __shfl_xor(cmax[c], m, 64));
            cmin[c] = fminf(cmin[c], __shfl_xor(cmin[c], m, 64));
        }
    }
    if (quad == 0) {  // lanes 0..15 hold col results
        #pragma unroll
        for (int c = 0; c < 4; ++c) {
            const int lc = wx * 64 + c * 16 + l15;
            atomicMax(&schp[lc], __float_as_int(cmax[c]));
            atomicMin(&schn[lc], __float_as_uint(cmin[c]));
        }
    }
    __syncthreads();
    if (tid < 128) {
        float rp = __int_as_float(srhp[tid]);
        float rn = __uint_as_float(srhn[tid]);
        const float cp = __int_as_float(schp[tid]);
        const float cn = __uint_as_float(schn[tid]);
        if (ib == jb) {
            pHP[(size_t)jb * BN + i0 + tid] = fmaxf(rp, cp);   // diagonal: combine
            pHN[(size_t)jb * BN + i0 + tid] = fminf(rn, cn);
        } else {
            pHP[(size_t)jb * BN + i0 + tid] = rp;   // row-part -> slot jb
            pHN[(size_t)jb * BN + i0 + tid] = rn;
            pHP[(size_t)ib * BN + j0 + tid] = cp;   // col-part -> slot ib
            pHN[(size_t)ib * BN + j0 + tid] = cn;
        }
    }
}

// ------- reduce: fold 32 d^2 partial slots per row (4-way parallel per row),
//         sqrt once, accumulate loss, last block finalizes ----------------------
__global__ __launch_bounds__(256) void tl_reduce(const float* __restrict__ pHP,
                                                 const float* __restrict__ pHN,
                                                 float* __restrict__ red,
                                                 float* __restrict__ out) {
    __shared__ float shp[4][64], shn[4][64];
    const int rl = threadIdx.x & 63;                 // row within block
    const int g  = threadIdx.x >> 6;                 // slot-group 0..3 (8 slots each)
    const int i  = blockIdx.x * 64 + rl;
    float hp2 = -1.0f, hn2 = NEG_FILL_F;
    #pragma unroll
    for (int q = 0; q < 8; ++q) {
        const int s = g * 8 + q;
        hp2 = fmaxf(hp2, pHP[(size_t)s * BN + i]);   // coalesced per 64-lane group
        hn2 = fminf(hn2, pHN[(size_t)s * BN + i]);
    }
    shp[g][rl] = hp2;
    shn[g][rl] = hn2;
    __syncthreads();
    if (g == 0) {                                    // wave 0 finishes 64 rows
        #pragma unroll
        for (int k = 1; k < 4; ++k) {
            hp2 = fmaxf(hp2, shp[k][rl]);
            hn2 = fminf(hn2, shn[k][rl]);
        }
        const bool valid = (hp2 >= 0.0f) && (hn2 < NEG_FILL_F);  // has_pos && has_neg
        const float hp = sqrtf(fmaxf(hp2, 0.0f));    // sqrt(max d^2) == max d (monotone)
        const float hn = sqrtf(hn2);
        const float per = fmaxf(hp - hn + MARGIN_F, 0.0f);
        float s_ = valid ? per : 0.0f;
        float c_ = valid ? 1.0f : 0.0f;
        #pragma unroll
        for (int m = 32; m; m >>= 1) {
            s_ += __shfl_xor(s_, m, 64);
            c_ += __shfl_xor(c_, m, 64);
        }
        if (rl == 0) {
            atomicAdd(&red[0], s_);
            atomicAdd(&red[1], c_);
            __threadfence();
            const unsigned ticket = atomicAdd(reinterpret_cast<unsigned*>(&red[2]), 1u);
            if (ticket == gridDim.x - 1) {           // last block finalizes
                const float S2 = atomicAdd(&red[0], 0.0f);   // atomic read (RMW-ordered)
                const float C2 = atomicAdd(&red[1], 0.0f);
                out[0] = (C2 > 0.0f) ? (S2 / fmaxf(C2, 1.0f)) : 0.0f;
            }
        }
    }
}

extern "C" void kernel_launch(void* const* d_in, const int* in_sizes, int n_in,
                              void* d_out, int out_size, void* d_ws, size_t ws_size,
                              hipStream_t stream) {
    const float* E      = (const float*)d_in[0];
    const int*   labels = (const int*)d_in[1];

    float*  ws    = (float*)d_ws;
    float*  norms = ws;                            // [4096] f32
    float*  red   = ws + 4096;                     // [3] f32 (sum, cnt, ticket)
    float*  pHP   = ws + 8192;                     // [32][4096] f32 = 512 KB (d^2)
    float*  pHN   = ws + 8192 + NBLK * BN;         // [32][4096] f32 = 512 KB (d^2)
    ushort* Eh    = (ushort*)(ws + 8192 + 2 * NBLK * BN);  // [32][4104][8] f16 ~ 2.0 MB

    tl_prep<<<BN / 4, 256, 0, stream>>>(E, norms, red, Eh);
    tl_main<<<NPAIR, 256, 0, stream>>>(Eh, labels, norms, pHP, pHN);
    tl_reduce<<<BN / 64, 256, 0, stream>>>(pHP, pHN, red, (float*)d_out);
}